// Round 7
// baseline (166.465 us; speedup 1.0000x reference)
//
#include <hip/hip_runtime.h>
#include <math.h>

#define HID    64
#define MSTEPS 60
#define NPTS   32
#define RPTSC  128
#define BTOT   (RPTSC*NPTS)    // 4096 paths
#define NSIM   (2*BTOT)        // 8192 path-branches
#define NWAVE  (NSIM/2)        // 4096 waves, 2 path-branches per wave
#define NBLK   (NWAVE/4)       // 1024 blocks

// hard-coded model constants (match reference, fp32 semantics)
#define C_DT     0.025f
#define C_SQDT   0.15811388300841897f   // sqrt(0.025)
#define C_ALPHA  0.8f
#define C_RHO    0.3f
#define C_SQ1MR2 0.9539392014169456f    // sqrt(1-0.09)
#define C_KAPPA  1.2f
#define C_R      0.02f
#define C_SIGMA  0.2f
#define C_SIGY   0.3f
#define C_LBW    1e-3f
#define C_LOGLBW -6.907755279f          // log(1e-3)
#define C_2L2E   2.8853900817779268f    // 2*log2(e): tanh(x)=1-2/(2^(x*2L2E)+1)

// per-wave LDS layout:
//   [0,2304)      A-buffer: 16 rows x 144 B (64 f16 + 16 B pad)
//   [2304,3328)   DV: per unit u: [u*16 + p*8] int2 of f16 (a0,aW | aY,aWW)
//   [3328,3584)   DA: per unit u: [u*4 + p*2] f16 aWY  (path-interleaved)
#define WAVE_LDS 3584
#define A_ROW    144
#define OFF_DV   2304
#define OFF_DA   3328

typedef _Float16 half8 __attribute__((ext_vector_type(8)));
typedef float    f32x4 __attribute__((ext_vector_type(4)));
typedef _Float16 h2    __attribute__((ext_vector_type(2)));

__device__ __forceinline__ float rlanef(float v, int l) {
    return __int_as_float(__builtin_amdgcn_readlane(__float_as_int(v), l));
}
// static-pattern lane crossbar within 32-lane groups (BitMode):
// src_lane = ((lane & and) | or) ^ xor ; offset = (xor<<10)|(or<<5)|and
template <int OFF>
__device__ __forceinline__ float swz(float v) {
    return __int_as_float(__builtin_amdgcn_ds_swizzle(__float_as_int(v), OFF));
}
__device__ __forceinline__ f32x4 MFMA(half8 a, half8 b, f32x4 c) {
    return __builtin_amdgcn_mfma_f32_16x16x32_f16(a, b, c, 0, 0, 0);
}
// pack two f32 -> f16x2 (RTZ) as int
__device__ __forceinline__ int pk16(float a, float b) {
    return __builtin_bit_cast(int, __builtin_amdgcn_cvt_pkrtz(a, b));
}
__device__ __forceinline__ h2 pk2(float a, float b) {
    return __builtin_bit_cast(h2, __builtin_amdgcn_cvt_pkrtz(a, b));
}
// v_perm_b32 byte gather: sel byte<4 picks from s1, >=4 picks from s0
__device__ __forceinline__ h2 permh(unsigned s0, unsigned s1, unsigned sel) {
    return __builtin_bit_cast(h2, __builtin_amdgcn_perm(s0, s1, sel));
}
// tanh with argument pre-scaled by 2*log2(e): tanh = 1 - 2/(2^xs + 1)
__device__ __forceinline__ float tanh_fast(float xs) {
    return 1.0f - 2.0f * __builtin_amdgcn_rcpf(__builtin_amdgcn_exp2f(xs) + 1.0f);
}

// sim: per-branch derivatives stored directly (no atomics, no zero-init).
// sd[c*NSIM + branch], branch = simb*BTOT + pg; branch & 31 == eval point.
__global__ __launch_bounds__(256, 4) void sim_kernel(
    const float* __restrict__ noise,
    const float* __restrict__ w1, const float* __restrict__ b1,
    const float* __restrict__ w2, const float* __restrict__ b2,
    const float* __restrict__ w3, const float* __restrict__ b3,
    const float* __restrict__ Wp, const float* __restrict__ Yp,
    float* __restrict__ sd)
{
    __shared__ __align__(16) char smem[4 * WAVE_LDS];
    const int lane = threadIdx.x & 63;
    const int quad = lane >> 4;      // 0..3
    const int mrow = lane & 15;      // 0..15
    const int par  = lane >> 5;      // path half: lanes 0-31 path0, 32-63 path1
    char* wb = smem + (threadIdx.x >> 6) * WAVE_LDS;

    const int w = __builtin_amdgcn_readfirstlane(
        (int)((blockIdx.x * blockDim.x + threadIdx.x) >> 6));   // 0..4095
    const int simb = w >> 11;                 // antithetic branch (uniform per wave)
    const int pg   = 2*(w & 2047) + par;      // per-lane global path 0..4095
    const int i    = pg & (NPTS - 1);         // per-lane eval point

    // per-lane layer-1 weights (lane = hidden unit)
    const float cW  = w1[lane];
    const float cT  = w1[HID + lane];
    const float cYw = w1[2*HID + lane];
    const float b1k = b1[lane];
    const float b2k = b2[lane];
    const float b3v = b3[0];
    // exp2-folded variants for tanh_fast
    const float cW_s  = cW  * C_2L2E;
    const float cT_s  = cT  * C_2L2E;
    const float cYw_s = cYw * C_2L2E;
    const float b1_s  = b1k * C_2L2E;
    const float b2_s  = b2k * C_2L2E;
    // packed-f16 jet constants (-2 folded into the ddp products)
    const h2 cWh  = pk2(cW, cW);
    const h2 cYwh = pk2(cYw, cYw);
    const h2 cW2m = pk2(-2.0f*cW*cW,  -2.0f*cW*cW);
    const h2 cWYm = pk2(-2.0f*cW*cYw, -2.0f*cW*cYw);
    const h2 hone = {(_Float16)1.0f,  (_Float16)1.0f};
    const h2 m2h  = {(_Float16)-2.0f, (_Float16)-2.0f};

    // MFMA B fragments (f16): B[k][n], n=mrow+t*16, k=q*32+quad*8+j
    half8 B00, B01, B02, B03, B10, B11, B12, B13, W30, W31;
    {
        half8 h;
        #define LOADB(dst, q, t) \
            { for (int j = 0; j < 8; ++j) \
                h[j] = (_Float16)w2[((q)*32 + quad*8 + j)*HID + (t)*16 + mrow]; \
              dst = h; }
        LOADB(B00, 0, 0) LOADB(B01, 0, 1) LOADB(B02, 0, 2) LOADB(B03, 0, 3)
        LOADB(B10, 1, 0) LOADB(B11, 1, 1) LOADB(B12, 1, 2) LOADB(B13, 1, 3)
        #undef LOADB
        for (int j = 0; j < 8; ++j) h[j] = (_Float16)w3[0*32 + quad*8 + j];
        W30 = h;
        for (int j = 0; j < 8; ++j) h[j] = (_Float16)w3[1*32 + quad*8 + j];
        W31 = h;
    }

    // zero A-buffer once (rows 5-7, 13-15 must stay zero)
    for (int off = lane*4; off < 16*A_ROW; off += 256)
        *(float*)(wb + off) = 0.0f;

    // LDS addresses
    _Float16* swp = (_Float16*)(wb + lane*2);   // + row*72 elements
    char* arp0 = wb + mrow*A_ROW + quad*16;     // A-frag k-iter 0 (+64 B for iter 1)

    // per-lane noise pointers (half-wave uniform)
    const float* zp1 = noise + (size_t)(simb*2 + 0) * MSTEPS * BTOT + pg;
    const float* zp2 = noise + (size_t)(simb*2 + 1) * MSTEPS * BTOT + pg;

    // ---- precomputed dynamics coefficients (fold anti & constants)
    const float anti = simb ? -1.0f : 1.0f;
    const float ksa  = C_SIGMA * C_ALPHA;
    const float ks2  = C_SIGMA * C_SIGMA;
    const float ksn  = anti * C_SIGMA * C_SQDT;
    const float kFy  = ksa * C_DT;
    const float ksd  = ks2 * C_DT;
    const float kv   = 0.5f * ks2 * C_DT;
    const float kRdt = C_R * C_DT;
    const float ky1  = anti * C_SIGY * C_SQDT * C_RHO;
    const float ky2  = anti * C_SIGY * C_SQDT * C_SQ1MR2;
    const float cYfac = 1.0f - C_KAPPA * C_DT;

    // per-lane path state + jets of L = logW
    const float W0 = Wp[i];
    float L   = __logf(fmaxf(W0, C_LBW));
    float W   = __expf(L);
    float Yv  = Yp[i];
    float tmt = 1.5f;
    float gW  = 1.0f / W0;
    float hWW = -gW * gW;
    float gY  = 0.0f, hWY = 0.0f;
    float cYt = 1.0f;

    // software-pipelined noise (issue next step's loads a full body ahead)
    float z1c = zp1[0];
    float z2c = zp2[0];

    #pragma unroll 1
    for (int m = 0; m < MSTEPS; ++m) {
        // AGPR-resident fragment pin: "+a" keeps the 10 B/W3 fragments in the
        // accumulator file across the loop (gfx950 MFMA reads A/B from AGPR
        // directly). The previous "+v" pin forced per-iteration
        // v_accvgpr_read/write round trips (VGPR_Count=52 cannot hold the 40
        // fragment VGPRs) -- pure VALU-issue waste on an issue-bound kernel.
        asm volatile("" : "+a"(B00), "+a"(B01), "+a"(B02), "+a"(B03),
                          "+a"(B10), "+a"(B11), "+a"(B12), "+a"(B13),
                          "+a"(W30), "+a"(W31));

        const float z1 = z1c, z2 = z2c;
        const int mn = (m + 1 < MSTEPS) ? m + 1 : m;
        z1c = zp1[(size_t)mn * BTOT];
        z2c = zp2[(size_t)mn * BTOT];

        // broadcast both paths' (W,Y): path0 state in lane 0, path1 in lane 32
        const float Wb0 = rlanef(W, 0),  Wb1 = rlanef(W, 32);
        const float Yb0 = rlanef(Yv, 0), Yb1 = rlanef(Yv, 32);

        // ---- layer 1 + tanh, both paths packed f16; marshal A rows 8p..8p+4
        const float base1s = fmaf(tmt, cT_s, b1_s);
        {
            const float t10 = tanh_fast(fmaf(Wb0, cW_s, fmaf(Yb0, cYw_s, base1s)));
            const float t11 = tanh_fast(fmaf(Wb1, cW_s, fmaf(Yb1, cYw_s, base1s)));
            const h2 tp  = pk2(t10, t11);
            const h2 dpp = hone - tp * tp;      // v_pk_fma
            const h2 ddq = tp * dpp;            // (-2) folded into cW2m/cWYm
            const h2 r1 = dpp * cWh;
            const h2 r2 = dpp * cYwh;
            const h2 r3 = ddq * cW2m;
            const h2 r4 = ddq * cWYm;
            swp[0*72] = tp.x;  swp[8*72]  = tp.y;   // hi halves -> ds_write_b16_d16_hi
            swp[1*72] = r1.x;  swp[9*72]  = r1.y;
            swp[2*72] = r2.x;  swp[10*72] = r2.y;
            swp[3*72] = r3.x;  swp[11*72] = r3.y;
            swp[4*72] = r4.x;  swp[12*72] = r4.y;
        }

        half8 af0 = __builtin_bit_cast(half8, *(const f32x4*)arp0);
        half8 af1 = __builtin_bit_cast(half8, *(const f32x4*)(arp0 + 64));

        // ---- layer 2 GEMM: 4 N-tiles x 2 K-iters
        f32x4 acc[4];
        const f32x4 zz = {0.f, 0.f, 0.f, 0.f};
        acc[0] = MFMA(af1, B10, MFMA(af0, B00, zz));
        acc[1] = MFMA(af1, B11, MFMA(af0, B01, zz));
        acc[2] = MFMA(af1, B12, MFMA(af0, B02, zz));
        acc[3] = MFMA(af1, B13, MFMA(af0, B03, zz));

        // ---- D transpose via LDS, packed f16, path-interleaved per unit
        {
            const int p = quad >> 1;
            if (!(quad & 1)) {
                #pragma unroll
                for (int t = 0; t < 4; ++t) {
                    int2 v;
                    v.x = pk16(acc[t].x, acc[t].y);
                    v.y = pk16(acc[t].z, acc[t].w);
                    *(int2*)(wb + OFF_DV + ((t*16 + mrow) << 4) + (p << 3)) = v;
                }
            } else {
                #pragma unroll
                for (int t = 0; t < 4; ++t)
                    *(_Float16*)(wb + OFF_DA + ((t*16 + mrow) << 2) + (p << 1)) =
                        (_Float16)acc[t].x;
            }
        }

        // ---- per-lane (unit k): one b128 + one b32 read, re-pair via v_perm
        const f32x4 dvv = *(const f32x4*)(wb + OFF_DV + lane*16);
        const h2 awyp   = *(const h2*)(wb + OFF_DA + lane*4);
        {
            const unsigned q0 = __builtin_bit_cast(unsigned, dvv.x); // p0 (a0,aW)
            const unsigned q1 = __builtin_bit_cast(unsigned, dvv.y); // p0 (aY,aWW)
            const unsigned q2 = __builtin_bit_cast(unsigned, dvv.z); // p1 (a0,aW)
            const unsigned q3 = __builtin_bit_cast(unsigned, dvv.w); // p1 (aY,aWW)
            const h2 a0p  = permh(q2, q0, 0x05040100);
            const h2 aWp  = permh(q2, q0, 0x07060302);
            const h2 aYp  = permh(q3, q1, 0x05040100);
            const h2 aWWp = permh(q3, q1, 0x07060302);

            const float t20 = tanh_fast(fmaf((float)a0p.x, C_2L2E, b2_s));
            const float t21 = tanh_fast(fmaf((float)a0p.y, C_2L2E, b2_s));
            const h2 t2p = pk2(t20, t21);
            const h2 d2p = hone - t2p * t2p;
            const h2 qp  = (m2h * (t2p * d2p)) * aWp;   // dd2 * aW
            const h2 s1 = d2p * aWp;
            const h2 s2 = d2p * aYp;
            const h2 s3 = qp * aWp + d2p * aWWp;
            const h2 s4 = qp * aYp + d2p * awyp;
            swp[0*72] = t2p.x; swp[8*72]  = t2p.y;
            swp[1*72] = s1.x;  swp[9*72]  = s1.y;
            swp[2*72] = s2.x;  swp[10*72] = s2.y;
            swp[3*72] = s3.x;  swp[11*72] = s3.y;
            swp[4*72] = s4.x;  swp[12*72] = s4.y;
        }

        // ---- layer 3 via MFMA (w3 broadcast over n -> all cols equal)
        half8 bf0 = __builtin_bit_cast(half8, *(const f32x4*)arp0);
        half8 bf1 = __builtin_bit_cast(half8, *(const f32x4*)(arp0 + 64));
        f32x4 acc4 = MFMA(bf1, W31, MFMA(bf0, W30, zz));

        // ---- policy-jet broadcast via ds_swizzle (static crossbar, 32-lane
        // groups — no LDS memory round trip, no bank conflicts):
        // rows 8p..8p+3 live in lane 32p regs x..w -> offset 0x0000 (group lane 0)
        // row 8p+4 lives in lane 32p+16 reg x      -> offset 0x0200 (group lane 16)
        const float pi  = swz<0x0000>(acc4.x) + b3v;
        const float pW  = swz<0x0000>(acc4.y);
        const float pY  = swz<0x0000>(acc4.z);
        const float pWW = swz<0x0000>(acc4.w);
        const float pWY = swz<0x0200>(acc4.x);

        // ---- dynamics + jet update (refactored: shared GdtSn factor)
        const float Sn    = ksn * z1;
        const float say   = ksa * Yv;
        const float G     = fmaf(-ks2, pi, say);
        const float GdtSn = fmaf(G, C_DT, Sn);

        const float w2v  = W * W;
        const float piL  = pW * W;
        const float piLL = fmaf(pWW, w2v, piL);
        const float piY  = pY;
        const float piLY = pWY * W;

        const float pi2  = pi * pi;
        const float Lnew = fmaf(pi, fmaf(say, C_DT, Sn),
                                fmaf(-kv, pi2, L + kRdt));

        const float F_L  = fmaf(piL, GdtSn, 1.0f);
        const float F_Y  = fmaf(piY, GdtSn, kFy * pi);
        const float piL2 = piL * piL;
        const float F_LL = fmaf(piLL, GdtSn, -(ksd * piL2));
        const float F_LY = fmaf(piLY, GdtSn, piL * fmaf(-ksd, piY, kFy));

        const float gW2  = gW * gW;
        const float hWWn = fmaf(F_LL, gW2, F_L * hWW);
        const float hWYn = fmaf(F_LL, gW * gY,
                                fmaf(F_LY, gW * cYt, F_L * hWY));
        const float gWn  = F_L * gW;
        const float gYn  = fmaf(F_Y, cYt, F_L * gY);

        Yv  = fmaf(ky2, z2, fmaf(ky1, z1, cYfac * Yv));
        cYt *= cYfac;

        const float We   = __expf(Lnew);
        const bool  clip = (We < C_LBW);
        L   = clip ? C_LOGLBW : Lnew;
        W   = clip ? C_LBW    : We;
        gW  = clip ? 0.0f : gWn;
        gY  = clip ? 0.0f : gYn;
        hWW = clip ? 0.0f : hWWn;
        hWY = clip ? 0.0f : hWYn;
        tmt -= C_DT;
    }

    // terminal utility U = -0.25*exp(-4L); direct per-branch store (no atomics)
    const float E   = __expf(-4.0f * L);
    const float d1  = E * gW;
    const float d2v = fmaf(-4.0f * E, gW * gW, E * hWW);
    const float d3v = fmaf(-4.0f * E, gW * gY, E * hWY);

    if ((lane & 31) == 0) {   // lane 0 = path 2w', lane 32 = path 2w'+1
        const int branch = simb * BTOT + pg;      // 0..8191, branch&31 == i
        sd[         branch] = 0.5f * d1;
        sd[  NSIM + branch] = 0.5f * d2v;
        sd[2*NSIM + branch] = 0.5f * d3v;
    }
}

// 512 threads: 16 chunk-accumulators per eval point, LDS tree reduce.
__global__ __launch_bounds__(512) void proj_kernel(
    const float* __restrict__ sd,
    const float* __restrict__ Wp,
    const float* __restrict__ Yp,
    float* __restrict__ out)
{
    __shared__ float red[3 * 512];
    const int tid = threadIdx.x;
    const int i = tid & 31;
    const int c = tid >> 5;           // 0..15
    float lam = 0.f, dW = 0.f, dY = 0.f;
    #pragma unroll 4
    for (int jj = 0; jj < 16; ++jj) {            // 256 chunks of 32 floats total
        const int idx = i + ((jj*16 + c) << 5);  // coalesced 128B per 32 lanes
        lam += sd[idx];
        dW  += sd[NSIM + idx];
        dY  += sd[2*NSIM + idx];
    }
    red[tid] = lam; red[512 + tid] = dW; red[1024 + tid] = dY;
    __syncthreads();
    if (tid < NPTS) {
        float l = 0.f, w = 0.f, y = 0.f;
        #pragma unroll
        for (int c2 = 0; c2 < 16; ++c2) {
            l += red[c2*32 + i];
            w += red[512 + c2*32 + i];
            y += red[1024 + c2*32 + i];
        }
        l *= (1.0f / 2097152.0f);     // /128^3
        w *= (1.0f / 268435456.0f);   // /128^4
        y *= (1.0f / 268435456.0f);
        const float Wv = Wp[i], Yv = Yp[i];
        const float mmr   = C_SIGMA * (C_ALPHA * Yv);
        const float sig2  = C_SIGMA * C_SIGMA;
        const float coeff = -1.0f / (Wv * w + 1e-8f);
        const float myo   = coeff * (l * (mmr / sig2));
        const float hedge = coeff * (C_SIGMA * C_RHO * C_SIGY * y / sig2);
        float v = myo + hedge;
        v = fminf(fmaxf(v, -2.0f), 2.0f);
        out[i] = v;
    }
}

extern "C" void kernel_launch(void* const* d_in, const int* in_sizes, int n_in,
                              void* d_out, int out_size, void* d_ws, size_t ws_size,
                              hipStream_t stream) {
    const float* Wp    = (const float*)d_in[0];
    // d_in[1] = TmT (unused: reference simulates from T_H constant)
    const float* Yp    = (const float*)d_in[2];
    const float* noise = (const float*)d_in[3];
    const float* w1    = (const float*)d_in[4];
    const float* b1    = (const float*)d_in[5];
    const float* w2    = (const float*)d_in[6];
    const float* b2    = (const float*)d_in[7];
    const float* w3    = (const float*)d_in[8];
    const float* b3    = (const float*)d_in[9];
    float* out = (float*)d_out;
    float* sd  = (float*)d_ws;   // 3*8192 floats = 96 KB staging

    hipLaunchKernelGGL(sim_kernel, dim3(NBLK), dim3(256), 0, stream,
                       noise, w1, b1, w2, b2, w3, b3, Wp, Yp, sd);
    hipLaunchKernelGGL(proj_kernel, dim3(1), dim3(512), 0, stream, sd, Wp, Yp, out);
}

// Round 9
// 161.157 us; speedup vs baseline: 1.0329x; 1.0329x over previous
//
#include <hip/hip_runtime.h>
#include <math.h>

#define HID    64
#define MSTEPS 60
#define NPTS   32
#define RPTSC  128
#define BTOT   (RPTSC*NPTS)    // 4096 paths
#define NSIM   (2*BTOT)        // 8192 path-branches
#define NWAVE  (NSIM/2)        // 4096 waves, 2 path-branches per wave
#define NBLK   (NWAVE/4)       // 1024 blocks

// hard-coded model constants (match reference, fp32 semantics)
#define C_DT     0.025f
#define C_SQDT   0.15811388300841897f   // sqrt(0.025)
#define C_ALPHA  0.8f
#define C_RHO    0.3f
#define C_SQ1MR2 0.9539392014169456f    // sqrt(1-0.09)
#define C_KAPPA  1.2f
#define C_R      0.02f
#define C_SIGMA  0.2f
#define C_SIGY   0.3f
#define C_LBW    1e-3f
#define C_LOGLBW -6.907755279f          // log(1e-3)
#define C_2L2E   2.8853900817779268f    // 2*log2(e): tanh(x)=1-2/(2^(x*2L2E)+1)

// per-wave LDS layout:
//   [0,2304)      A-buffer: 16 rows x 144 B (64 f16 + 16 B pad)
//   [2304,3328)   DV: per unit u: [u*16 + p*8] int2 of f16 (a0,aW | aY,aWW)
//   [3328,3584)   DA: per unit u: [u*4 + p*2] f16 aWY  (path-interleaved)
#define WAVE_LDS 3584
#define A_ROW    144
#define OFF_DV   2304
#define OFF_DA   3328

typedef _Float16 half8 __attribute__((ext_vector_type(8)));
typedef float    f32x4 __attribute__((ext_vector_type(4)));
typedef _Float16 h2    __attribute__((ext_vector_type(2)));

__device__ __forceinline__ float rlanef(float v, int l) {
    return __int_as_float(__builtin_amdgcn_readlane(__float_as_int(v), l));
}
// static-pattern lane crossbar within 32-lane groups (BitMode):
// src_lane = ((lane & and) | or) ^ xor ; offset = (xor<<10)|(or<<5)|and
template <int OFF>
__device__ __forceinline__ float swz(float v) {
    return __int_as_float(__builtin_amdgcn_ds_swizzle(__float_as_int(v), OFF));
}
__device__ __forceinline__ f32x4 MFMA(half8 a, half8 b, f32x4 c) {
    return __builtin_amdgcn_mfma_f32_16x16x32_f16(a, b, c, 0, 0, 0);
}
// pack two f32 -> f16x2 (RTZ) as int
__device__ __forceinline__ int pk16(float a, float b) {
    return __builtin_bit_cast(int, __builtin_amdgcn_cvt_pkrtz(a, b));
}
__device__ __forceinline__ h2 pk2(float a, float b) {
    return __builtin_bit_cast(h2, __builtin_amdgcn_cvt_pkrtz(a, b));
}
// v_perm_b32 byte gather: sel byte<4 picks from s1, >=4 picks from s0
__device__ __forceinline__ h2 permh(unsigned s0, unsigned s1, unsigned sel) {
    return __builtin_bit_cast(h2, __builtin_amdgcn_perm(s0, s1, sel));
}
// tanh with argument pre-scaled by 2*log2(e): tanh = 1 - 2/(2^xs + 1)
__device__ __forceinline__ float tanh_fast(float xs) {
    return 1.0f - 2.0f * __builtin_amdgcn_rcpf(__builtin_amdgcn_exp2f(xs) + 1.0f);
}

// sim: per-branch derivatives stored directly (no atomics, no zero-init).
// sd[c*NSIM + branch], branch = simb*BTOT + pg; branch & 31 == eval point.
__global__ __launch_bounds__(256, 4) void sim_kernel(
    const float* __restrict__ noise,
    const float* __restrict__ w1, const float* __restrict__ b1,
    const float* __restrict__ w2, const float* __restrict__ b2,
    const float* __restrict__ w3, const float* __restrict__ b3,
    const float* __restrict__ Wp, const float* __restrict__ Yp,
    float* __restrict__ sd)
{
    __shared__ __align__(16) char smem[4 * WAVE_LDS];
    const int lane = threadIdx.x & 63;
    const int quad = lane >> 4;      // 0..3
    const int mrow = lane & 15;      // 0..15
    const int par  = lane >> 5;      // path half: lanes 0-31 path0, 32-63 path1
    char* wb = smem + (threadIdx.x >> 6) * WAVE_LDS;

    const int w = __builtin_amdgcn_readfirstlane(
        (int)((blockIdx.x * blockDim.x + threadIdx.x) >> 6));   // 0..4095
    const int simb = w >> 11;                 // antithetic branch (uniform per wave)
    const int pg   = 2*(w & 2047) + par;      // per-lane global path 0..4095
    const int i    = pg & (NPTS - 1);         // per-lane eval point

    // per-lane layer-1 weights (lane = hidden unit)
    const float cW  = w1[lane];
    const float cT  = w1[HID + lane];
    const float cYw = w1[2*HID + lane];
    const float b1k = b1[lane];
    const float b2k = b2[lane];
    const float b3v = b3[0];
    // exp2-folded variants for tanh_fast
    const float cW_s  = cW  * C_2L2E;
    const float cT_s  = cT  * C_2L2E;
    const float cYw_s = cYw * C_2L2E;
    const float b1_s  = b1k * C_2L2E;
    const float b2_s  = b2k * C_2L2E;
    // packed-f16 jet constants (-2 folded into the ddp products)
    const h2 cWh  = pk2(cW, cW);
    const h2 cYwh = pk2(cYw, cYw);
    const h2 cW2m = pk2(-2.0f*cW*cW,  -2.0f*cW*cW);
    const h2 cWYm = pk2(-2.0f*cW*cYw, -2.0f*cW*cYw);
    const h2 hone = {(_Float16)1.0f,  (_Float16)1.0f};
    const h2 m2h  = {(_Float16)-2.0f, (_Float16)-2.0f};

    // MFMA B fragments (f16): B[k][n], n=mrow+t*16, k=q*32+quad*8+j
    half8 B00, B01, B02, B03, B10, B11, B12, B13, W30, W31;
    {
        half8 h;
        #define LOADB(dst, q, t) \
            { for (int j = 0; j < 8; ++j) \
                h[j] = (_Float16)w2[((q)*32 + quad*8 + j)*HID + (t)*16 + mrow]; \
              dst = h; }
        LOADB(B00, 0, 0) LOADB(B01, 0, 1) LOADB(B02, 0, 2) LOADB(B03, 0, 3)
        LOADB(B10, 1, 0) LOADB(B11, 1, 1) LOADB(B12, 1, 2) LOADB(B13, 1, 3)
        #undef LOADB
        for (int j = 0; j < 8; ++j) h[j] = (_Float16)w3[0*32 + quad*8 + j];
        W30 = h;
        for (int j = 0; j < 8; ++j) h[j] = (_Float16)w3[1*32 + quad*8 + j];
        W31 = h;
    }

    // ONE-TIME fragment materialization barrier (outside the loop).
    // The previous in-loop "+v" pin forced per-iteration re-materialization
    // into VGPRs: with VGPR_Count=52 the 40 fragment VGPRs cannot be resident,
    // so the compiler shuttled them (AGPR<->VGPR) every step -- hidden VALU
    // issue on an issue-bound kernel (R7's "+a" variant proved the copies:
    // forcing AGPR residence added copies at each MFMA use and cost 4 us).
    // Outside the loop, the values are plain loop-invariant SSA; at
    // launch_bounds(256,4) the 128-VGPR budget fits frags (40) + state (~55),
    // so regalloc keeps them VGPR-resident with zero per-iteration copies.
    asm volatile("" : "+v"(B00), "+v"(B01), "+v"(B02), "+v"(B03),
                      "+v"(B10), "+v"(B11), "+v"(B12), "+v"(B13),
                      "+v"(W30), "+v"(W31));

    // zero A-buffer once (rows 5-7, 13-15 must stay zero)
    for (int off = lane*4; off < 16*A_ROW; off += 256)
        *(float*)(wb + off) = 0.0f;

    // LDS addresses
    _Float16* swp = (_Float16*)(wb + lane*2);   // + row*72 elements
    char* arp0 = wb + mrow*A_ROW + quad*16;     // A-frag k-iter 0 (+64 B for iter 1)

    // per-lane noise pointers (half-wave uniform)
    const float* zp1 = noise + (size_t)(simb*2 + 0) * MSTEPS * BTOT + pg;
    const float* zp2 = noise + (size_t)(simb*2 + 1) * MSTEPS * BTOT + pg;

    // ---- precomputed dynamics coefficients (fold anti & constants)
    const float anti = simb ? -1.0f : 1.0f;
    const float ksa  = C_SIGMA * C_ALPHA;
    const float ks2  = C_SIGMA * C_SIGMA;
    const float ksn  = anti * C_SIGMA * C_SQDT;
    const float kFy  = ksa * C_DT;
    const float ksd  = ks2 * C_DT;
    const float kv   = 0.5f * ks2 * C_DT;
    const float kRdt = C_R * C_DT;
    const float ky1  = anti * C_SIGY * C_SQDT * C_RHO;
    const float ky2  = anti * C_SIGY * C_SQDT * C_SQ1MR2;
    const float cYfac = 1.0f - C_KAPPA * C_DT;

    // per-lane path state + jets of L = logW
    const float W0 = Wp[i];
    float L   = __logf(fmaxf(W0, C_LBW));
    float W   = __expf(L);
    float Yv  = Yp[i];
    float tmt = 1.5f;
    float gW  = 1.0f / W0;
    float hWW = -gW * gW;
    float gY  = 0.0f, hWY = 0.0f;
    float cYt = 1.0f;

    #pragma unroll 1
    for (int m = 0; m < MSTEPS; ++m) {
        const float z1 = zp1[(size_t)m * BTOT];
        const float z2 = zp2[(size_t)m * BTOT];

        // broadcast both paths' (W,Y): path0 state in lane 0, path1 in lane 32
        const float Wb0 = rlanef(W, 0),  Wb1 = rlanef(W, 32);
        const float Yb0 = rlanef(Yv, 0), Yb1 = rlanef(Yv, 32);

        // ---- layer 1 + tanh, both paths packed f16; marshal A rows 8p..8p+4
        const float base1s = fmaf(tmt, cT_s, b1_s);
        {
            const float t10 = tanh_fast(fmaf(Wb0, cW_s, fmaf(Yb0, cYw_s, base1s)));
            const float t11 = tanh_fast(fmaf(Wb1, cW_s, fmaf(Yb1, cYw_s, base1s)));
            const h2 tp  = pk2(t10, t11);
            const h2 dpp = hone - tp * tp;      // v_pk_fma
            const h2 ddq = tp * dpp;            // (-2) folded into cW2m/cWYm
            const h2 r1 = dpp * cWh;
            const h2 r2 = dpp * cYwh;
            const h2 r3 = ddq * cW2m;
            const h2 r4 = ddq * cWYm;
            swp[0*72] = tp.x;  swp[8*72]  = tp.y;   // hi halves -> ds_write_b16_d16_hi
            swp[1*72] = r1.x;  swp[9*72]  = r1.y;
            swp[2*72] = r2.x;  swp[10*72] = r2.y;
            swp[3*72] = r3.x;  swp[11*72] = r3.y;
            swp[4*72] = r4.x;  swp[12*72] = r4.y;
        }

        half8 af0 = __builtin_bit_cast(half8, *(const f32x4*)arp0);
        half8 af1 = __builtin_bit_cast(half8, *(const f32x4*)(arp0 + 64));

        // ---- layer 2 GEMM: 4 N-tiles x 2 K-iters
        f32x4 acc[4];
        const f32x4 zz = {0.f, 0.f, 0.f, 0.f};
        acc[0] = MFMA(af1, B10, MFMA(af0, B00, zz));
        acc[1] = MFMA(af1, B11, MFMA(af0, B01, zz));
        acc[2] = MFMA(af1, B12, MFMA(af0, B02, zz));
        acc[3] = MFMA(af1, B13, MFMA(af0, B03, zz));

        // ---- D transpose via LDS, packed f16, path-interleaved per unit
        {
            const int p = quad >> 1;
            if (!(quad & 1)) {
                #pragma unroll
                for (int t = 0; t < 4; ++t) {
                    int2 v;
                    v.x = pk16(acc[t].x, acc[t].y);
                    v.y = pk16(acc[t].z, acc[t].w);
                    *(int2*)(wb + OFF_DV + ((t*16 + mrow) << 4) + (p << 3)) = v;
                }
            } else {
                #pragma unroll
                for (int t = 0; t < 4; ++t)
                    *(_Float16*)(wb + OFF_DA + ((t*16 + mrow) << 2) + (p << 1)) =
                        (_Float16)acc[t].x;
            }
        }

        // ---- per-lane (unit k): one b128 + one b32 read, re-pair via v_perm
        const f32x4 dvv = *(const f32x4*)(wb + OFF_DV + lane*16);
        const h2 awyp   = *(const h2*)(wb + OFF_DA + lane*4);
        {
            const unsigned q0 = __builtin_bit_cast(unsigned, dvv.x); // p0 (a0,aW)
            const unsigned q1 = __builtin_bit_cast(unsigned, dvv.y); // p0 (aY,aWW)
            const unsigned q2 = __builtin_bit_cast(unsigned, dvv.z); // p1 (a0,aW)
            const unsigned q3 = __builtin_bit_cast(unsigned, dvv.w); // p1 (aY,aWW)
            const h2 a0p  = permh(q2, q0, 0x05040100);
            const h2 aWp  = permh(q2, q0, 0x07060302);
            const h2 aYp  = permh(q3, q1, 0x05040100);
            const h2 aWWp = permh(q3, q1, 0x07060302);

            const float t20 = tanh_fast(fmaf((float)a0p.x, C_2L2E, b2_s));
            const float t21 = tanh_fast(fmaf((float)a0p.y, C_2L2E, b2_s));
            const h2 t2p = pk2(t20, t21);
            const h2 d2p = hone - t2p * t2p;
            const h2 qp  = (m2h * (t2p * d2p)) * aWp;   // dd2 * aW
            const h2 s1 = d2p * aWp;
            const h2 s2 = d2p * aYp;
            const h2 s3 = qp * aWp + d2p * aWWp;
            const h2 s4 = qp * aYp + d2p * awyp;
            swp[0*72] = t2p.x; swp[8*72]  = t2p.y;
            swp[1*72] = s1.x;  swp[9*72]  = s1.y;
            swp[2*72] = s2.x;  swp[10*72] = s2.y;
            swp[3*72] = s3.x;  swp[11*72] = s3.y;
            swp[4*72] = s4.x;  swp[12*72] = s4.y;
        }

        // ---- layer 3 via MFMA (w3 broadcast over n -> all cols equal)
        half8 bf0 = __builtin_bit_cast(half8, *(const f32x4*)arp0);
        half8 bf1 = __builtin_bit_cast(half8, *(const f32x4*)(arp0 + 64));
        f32x4 acc4 = MFMA(bf1, W31, MFMA(bf0, W30, zz));

        // ---- policy-jet broadcast via ds_swizzle (static crossbar, 32-lane
        // groups — no LDS memory round trip, no bank conflicts):
        // rows 8p..8p+3 live in lane 32p regs x..w -> offset 0x0000 (group lane 0)
        // row 8p+4 lives in lane 32p+16 reg x      -> offset 0x0200 (group lane 16)
        const float pi  = swz<0x0000>(acc4.x) + b3v;
        const float pW  = swz<0x0000>(acc4.y);
        const float pY  = swz<0x0000>(acc4.z);
        const float pWW = swz<0x0000>(acc4.w);
        const float pWY = swz<0x0200>(acc4.x);

        // ---- dynamics + jet update (refactored: shared GdtSn factor)
        const float Sn    = ksn * z1;
        const float say   = ksa * Yv;
        const float G     = fmaf(-ks2, pi, say);
        const float GdtSn = fmaf(G, C_DT, Sn);

        const float w2v  = W * W;
        const float piL  = pW * W;
        const float piLL = fmaf(pWW, w2v, piL);
        const float piY  = pY;
        const float piLY = pWY * W;

        const float pi2  = pi * pi;
        const float Lnew = fmaf(pi, fmaf(say, C_DT, Sn),
                                fmaf(-kv, pi2, L + kRdt));

        const float F_L  = fmaf(piL, GdtSn, 1.0f);
        const float F_Y  = fmaf(piY, GdtSn, kFy * pi);
        const float piL2 = piL * piL;
        const float F_LL = fmaf(piLL, GdtSn, -(ksd * piL2));
        const float F_LY = fmaf(piLY, GdtSn, piL * fmaf(-ksd, piY, kFy));

        const float gW2  = gW * gW;
        const float hWWn = fmaf(F_LL, gW2, F_L * hWW);
        const float hWYn = fmaf(F_LL, gW * gY,
                                fmaf(F_LY, gW * cYt, F_L * hWY));
        const float gWn  = F_L * gW;
        const float gYn  = fmaf(F_Y, cYt, F_L * gY);

        Yv  = fmaf(ky2, z2, fmaf(ky1, z1, cYfac * Yv));
        cYt *= cYfac;

        const float We   = __expf(Lnew);
        const bool  clip = (We < C_LBW);
        L   = clip ? C_LOGLBW : Lnew;
        W   = clip ? C_LBW    : We;
        gW  = clip ? 0.0f : gWn;
        gY  = clip ? 0.0f : gYn;
        hWW = clip ? 0.0f : hWWn;
        hWY = clip ? 0.0f : hWYn;
        tmt -= C_DT;
    }

    // terminal utility U = -0.25*exp(-4L); direct per-branch store (no atomics)
    const float E   = __expf(-4.0f * L);
    const float d1  = E * gW;
    const float d2v = fmaf(-4.0f * E, gW * gW, E * hWW);
    const float d3v = fmaf(-4.0f * E, gW * gY, E * hWY);

    if ((lane & 31) == 0) {   // lane 0 = path 2w', lane 32 = path 2w'+1
        const int branch = simb * BTOT + pg;      // 0..8191, branch&31 == i
        sd[         branch] = 0.5f * d1;
        sd[  NSIM + branch] = 0.5f * d2v;
        sd[2*NSIM + branch] = 0.5f * d3v;
    }
}

// 512 threads: 16 chunk-accumulators per eval point, LDS tree reduce.
__global__ __launch_bounds__(512) void proj_kernel(
    const float* __restrict__ sd,
    const float* __restrict__ Wp,
    const float* __restrict__ Yp,
    float* __restrict__ out)
{
    __shared__ float red[3 * 512];
    const int tid = threadIdx.x;
    const int i = tid & 31;
    const int c = tid >> 5;           // 0..15
    float lam = 0.f, dW = 0.f, dY = 0.f;
    #pragma unroll 4
    for (int jj = 0; jj < 16; ++jj) {            // 256 chunks of 32 floats total
        const int idx = i + ((jj*16 + c) << 5);  // coalesced 128B per 32 lanes
        lam += sd[idx];
        dW  += sd[NSIM + idx];
        dY  += sd[2*NSIM + idx];
    }
    red[tid] = lam; red[512 + tid] = dW; red[1024 + tid] = dY;
    __syncthreads();
    if (tid < NPTS) {
        float l = 0.f, w = 0.f, y = 0.f;
        #pragma unroll
        for (int c2 = 0; c2 < 16; ++c2) {
            l += red[c2*32 + i];
            w += red[512 + c2*32 + i];
            y += red[1024 + c2*32 + i];
        }
        l *= (1.0f / 2097152.0f);     // /128^3
        w *= (1.0f / 268435456.0f);   // /128^4
        y *= (1.0f / 268435456.0f);
        const float Wv = Wp[i], Yv = Yp[i];
        const float mmr   = C_SIGMA * (C_ALPHA * Yv);
        const float sig2  = C_SIGMA * C_SIGMA;
        const float coeff = -1.0f / (Wv * w + 1e-8f);
        const float myo   = coeff * (l * (mmr / sig2));
        const float hedge = coeff * (C_SIGMA * C_RHO * C_SIGY * y / sig2);
        float v = myo + hedge;
        v = fminf(fmaxf(v, -2.0f), 2.0f);
        out[i] = v;
    }
}

extern "C" void kernel_launch(void* const* d_in, const int* in_sizes, int n_in,
                              void* d_out, int out_size, void* d_ws, size_t ws_size,
                              hipStream_t stream) {
    const float* Wp    = (const float*)d_in[0];
    // d_in[1] = TmT (unused: reference simulates from T_H constant)
    const float* Yp    = (const float*)d_in[2];
    const float* noise = (const float*)d_in[3];
    const float* w1    = (const float*)d_in[4];
    const float* b1    = (const float*)d_in[5];
    const float* w2    = (const float*)d_in[6];
    const float* b2    = (const float*)d_in[7];
    const float* w3    = (const float*)d_in[8];
    const float* b3    = (const float*)d_in[9];
    float* out = (float*)d_out;
    float* sd  = (float*)d_ws;   // 3*8192 floats = 96 KB staging

    hipLaunchKernelGGL(sim_kernel, dim3(NBLK), dim3(256), 0, stream,
                       noise, w1, b1, w2, b2, w3, b3, Wp, Yp, sd);
    hipLaunchKernelGGL(proj_kernel, dim3(1), dim3(512), 0, stream, sd, Wp, Yp, out);
}

// Round 10
// 158.083 us; speedup vs baseline: 1.0530x; 1.0194x over previous
//
#include <hip/hip_runtime.h>
#include <math.h>

#define HID    64
#define MSTEPS 60
#define NPTS   32
#define RPTSC  128
#define BTOT   (RPTSC*NPTS)    // 4096 paths
#define NSIM   (2*BTOT)        // 8192 path-branches
#define NWAVE  (NSIM/2)        // 4096 waves, 2 path-branches per wave
#define NBLK   (NWAVE/4)       // 1024 blocks

// hard-coded model constants (match reference, fp32 semantics)
#define C_DT     0.025f
#define C_SQDT   0.15811388300841897f   // sqrt(0.025)
#define C_ALPHA  0.8f
#define C_RHO    0.3f
#define C_SQ1MR2 0.9539392014169456f    // sqrt(1-0.09)
#define C_KAPPA  1.2f
#define C_R      0.02f
#define C_SIGMA  0.2f
#define C_SIGY   0.3f
#define C_LBW    1e-3f
#define C_LOGLBW -6.907755279f          // log(1e-3)
#define C_2L2E   2.8853900817779268f    // 2*log2(e): tanh(x)=1-2/(2^(x*2L2E)+1)

// per-wave LDS layout:
//   [0,2304)      S: jets unit-major for tr-read. 16 groups x 144 B; group g
//                 holds units 4g..4g+3 as 4 x 32 B (16 f16 rows each) + 16 B pad.
//                 Unit u at (u>>2)*144 + (u&3)*32. The 144 stride spreads the
//                 b128 writes over 8 start-banks (optimal: 1024 B >= 8 LDS cy).
//   [2304,3328)   DV: per unit u: [u*16 + p*8] int2 of f16 (a0,aW | aY,aWW)
//   [3328,3584)   DA: per unit u: [u*4 + p*2] f16 aWY  (path-interleaved)
#define WAVE_LDS 3584
#define OFF_DV   2304
#define OFF_DA   3328

typedef _Float16 half8 __attribute__((ext_vector_type(8)));
typedef float    f32x4 __attribute__((ext_vector_type(4)));
typedef _Float16 h2    __attribute__((ext_vector_type(2)));
typedef int      i32x2 __attribute__((ext_vector_type(2)));
typedef int      i32x4 __attribute__((ext_vector_type(4)));

__device__ __forceinline__ float rlanef(float v, int l) {
    return __int_as_float(__builtin_amdgcn_readlane(__float_as_int(v), l));
}
// static-pattern lane crossbar within 32-lane groups (BitMode):
// src_lane = ((lane & and) | or) ^ xor ; offset = (xor<<10)|(or<<5)|and
template <int OFF>
__device__ __forceinline__ float swz(float v) {
    return __int_as_float(__builtin_amdgcn_ds_swizzle(__float_as_int(v), OFF));
}
__device__ __forceinline__ f32x4 MFMA(half8 a, half8 b, f32x4 c) {
    return __builtin_amdgcn_mfma_f32_16x16x32_f16(a, b, c, 0, 0, 0);
}
// pack two f32 -> f16x2 (RTZ) as int
__device__ __forceinline__ int pk16(float a, float b) {
    return __builtin_bit_cast(int, __builtin_amdgcn_cvt_pkrtz(a, b));
}
__device__ __forceinline__ h2 pk2(float a, float b) {
    return __builtin_bit_cast(h2, __builtin_amdgcn_cvt_pkrtz(a, b));
}
// v_perm_b32 byte gather: sel byte<4 picks from s1, >=4 picks from s0
__device__ __forceinline__ unsigned permu(unsigned s0, unsigned s1, unsigned sel) {
    return __builtin_amdgcn_perm(s0, s1, sel);
}
__device__ __forceinline__ h2 permh(unsigned s0, unsigned s1, unsigned sel) {
    return __builtin_bit_cast(h2, __builtin_amdgcn_perm(s0, s1, sel));
}
// tanh with argument pre-scaled by 2*log2(e): tanh = 1 - 2/(2^xs + 1)
__device__ __forceinline__ float tanh_fast(float xs) {
    return 1.0f - 2.0f * __builtin_amdgcn_rcpf(__builtin_amdgcn_exp2f(xs) + 1.0f);
}
// gfx950 HW transpose read: lane reads 4 f16 at addr + j*32 B (j=0..3) --
// i.e. column (addr&31)/2 of a 4x16 f16 row-major tile. addr = 32-bit LDS
// byte offset (low 32 bits of a generic LDS pointer).
__device__ __forceinline__ i32x2 tr16(unsigned a) {
    i32x2 d;
    asm volatile("ds_read_b64_tr_b16 %0, %1"
                 : "=&v"(d) : "v"(a) : "memory");
    return d;
}
// guide rule #18: inline-asm ds_read needs lgkmcnt(0) + sched_barrier(0)
// before register-only consumers (hipcc hoists MFMA past asm waitcnt).
#define LGKM0_FENCE() do { \
    asm volatile("s_waitcnt lgkmcnt(0)" ::: "memory"); \
    __builtin_amdgcn_sched_barrier(0); } while (0)

// sim: per-branch derivatives stored directly (no atomics, no zero-init).
// sd[c*NSIM + branch], branch = simb*BTOT + pg; branch & 31 == eval point.
__global__ __launch_bounds__(256, 4) void sim_kernel(
    const float* __restrict__ noise,
    const float* __restrict__ w1, const float* __restrict__ b1,
    const float* __restrict__ w2, const float* __restrict__ b2,
    const float* __restrict__ w3, const float* __restrict__ b3,
    const float* __restrict__ Wp, const float* __restrict__ Yp,
    float* __restrict__ sd)
{
    __shared__ __align__(16) char smem[4 * WAVE_LDS];
    const int lane = threadIdx.x & 63;
    const int quad = lane >> 4;      // 0..3
    const int mrow = lane & 15;      // 0..15
    const int par  = lane >> 5;      // path half: lanes 0-31 path0, 32-63 path1
    char* wb = smem + (threadIdx.x >> 6) * WAVE_LDS;

    const int w = __builtin_amdgcn_readfirstlane(
        (int)((blockIdx.x * blockDim.x + threadIdx.x) >> 6));   // 0..4095
    const int simb = w >> 11;                 // antithetic branch (uniform per wave)
    const int pg   = 2*(w & 2047) + par;      // per-lane global path 0..4095
    const int i    = pg & (NPTS - 1);         // per-lane eval point

    // per-lane layer-1 weights (lane = hidden unit)
    const float cW  = w1[lane];
    const float cT  = w1[HID + lane];
    const float cYw = w1[2*HID + lane];
    const float b1k = b1[lane];
    const float b2k = b2[lane];
    const float b3v = b3[0];
    // exp2-folded variants for tanh_fast
    const float cW_s  = cW  * C_2L2E;
    const float cT_s  = cT  * C_2L2E;
    const float cYw_s = cYw * C_2L2E;
    const float b1_s  = b1k * C_2L2E;
    const float b2_s  = b2k * C_2L2E;
    // packed-f16 jet constants (-2 folded into the ddp products)
    const h2 cWh  = pk2(cW, cW);
    const h2 cYwh = pk2(cYw, cYw);
    const h2 cW2m = pk2(-2.0f*cW*cW,  -2.0f*cW*cW);
    const h2 cWYm = pk2(-2.0f*cW*cYw, -2.0f*cW*cYw);
    const h2 hone = {(_Float16)1.0f,  (_Float16)1.0f};
    const h2 m2h  = {(_Float16)-2.0f, (_Float16)-2.0f};

    // MFMA B fragments (f16): B[k][n], n=mrow+t*16, k=q*32+quad*8+j
    half8 B00, B01, B02, B03, B10, B11, B12, B13, W30, W31;
    {
        half8 h;
        #define LOADB(dst, q, t) \
            { for (int j = 0; j < 8; ++j) \
                h[j] = (_Float16)w2[((q)*32 + quad*8 + j)*HID + (t)*16 + mrow]; \
              dst = h; }
        LOADB(B00, 0, 0) LOADB(B01, 0, 1) LOADB(B02, 0, 2) LOADB(B03, 0, 3)
        LOADB(B10, 1, 0) LOADB(B11, 1, 1) LOADB(B12, 1, 2) LOADB(B13, 1, 3)
        #undef LOADB
        for (int j = 0; j < 8; ++j) h[j] = (_Float16)w3[0*32 + quad*8 + j];
        W30 = h;
        for (int j = 0; j < 8; ++j) h[j] = (_Float16)w3[1*32 + quad*8 + j];
        W31 = h;
    }
    // one-time materialization barrier (outside the loop; R9: neutral)
    asm volatile("" : "+v"(B00), "+v"(B01), "+v"(B02), "+v"(B03),
                      "+v"(B10), "+v"(B11), "+v"(B12), "+v"(B13),
                      "+v"(W30), "+v"(W31));

    // LDS addresses
    // S writer: this lane's (unit's) 32 B column, 2 x b128 per marshal
    char* Swp = wb + (lane >> 2) * 144 + (lane & 3) * 32;
    // S tr-readers: af0 = units quad*8+0..7 rows mrow -> groups 2q, 2q+1;
    // af1 = units 32+quad*8.. -> +8 groups (+1152 B)
    const unsigned wbu  = (unsigned)(size_t)wb;   // low 32 bits = LDS offset
    const unsigned tA0 = wbu + quad*288 + mrow*2;
    const unsigned tA1 = tA0 + 144;
    const unsigned tB0 = tA0 + 1152;
    const unsigned tB1 = tA0 + 1296;

    // per-lane noise pointers (half-wave uniform)
    const float* zp1 = noise + (size_t)(simb*2 + 0) * MSTEPS * BTOT + pg;
    const float* zp2 = noise + (size_t)(simb*2 + 1) * MSTEPS * BTOT + pg;

    // ---- precomputed dynamics coefficients (fold anti & constants)
    const float anti = simb ? -1.0f : 1.0f;
    const float ksa  = C_SIGMA * C_ALPHA;
    const float ks2  = C_SIGMA * C_SIGMA;
    const float ksn  = anti * C_SIGMA * C_SQDT;
    const float kFy  = ksa * C_DT;
    const float ksd  = ks2 * C_DT;
    const float kv   = 0.5f * ks2 * C_DT;
    const float kRdt = C_R * C_DT;
    const float ky1  = anti * C_SIGY * C_SQDT * C_RHO;
    const float ky2  = anti * C_SIGY * C_SQDT * C_SQ1MR2;
    const float cYfac = 1.0f - C_KAPPA * C_DT;

    // per-lane path state + jets of L = logW
    const float W0 = Wp[i];
    float L   = __logf(fmaxf(W0, C_LBW));
    float W   = __expf(L);
    float Yv  = Yp[i];
    float tmt = 1.5f;
    float gW  = 1.0f / W0;
    float hWW = -gW * gW;
    float gY  = 0.0f, hWY = 0.0f;
    float cYt = 1.0f;

    #pragma unroll 1
    for (int m = 0; m < MSTEPS; ++m) {
        const float z1 = zp1[(size_t)m * BTOT];
        const float z2 = zp2[(size_t)m * BTOT];

        // broadcast both paths' (W,Y): path0 state in lane 0, path1 in lane 32
        const float Wb0 = rlanef(W, 0),  Wb1 = rlanef(W, 32);
        const float Yb0 = rlanef(Yv, 0), Yb1 = rlanef(Yv, 32);

        // ---- layer 1 + tanh, both paths packed f16; marshal this unit's
        // S-column [tp,r1,r2,r3,r4,0,0,0 | p1...] as 2 x ds_write_b128
        const float base1s = fmaf(tmt, cT_s, b1_s);
        {
            const float t10 = tanh_fast(fmaf(Wb0, cW_s, fmaf(Yb0, cYw_s, base1s)));
            const float t11 = tanh_fast(fmaf(Wb1, cW_s, fmaf(Yb1, cYw_s, base1s)));
            const h2 tp  = pk2(t10, t11);
            const h2 dpp = hone - tp * tp;      // v_pk_fma
            const h2 ddq = tp * dpp;            // (-2) folded into cW2m/cWYm
            const h2 r1 = dpp * cWh;
            const h2 r2 = dpp * cYwh;
            const h2 r3 = ddq * cW2m;
            const h2 r4 = ddq * cWYm;
            const unsigned utp = __builtin_bit_cast(unsigned, tp);
            const unsigned ur1 = __builtin_bit_cast(unsigned, r1);
            const unsigned ur2 = __builtin_bit_cast(unsigned, r2);
            const unsigned ur3 = __builtin_bit_cast(unsigned, r3);
            const unsigned ur4 = __builtin_bit_cast(unsigned, r4);
            i32x4 lo, hi;
            lo[0] = (int)permu(ur1, utp, 0x05040100u);   // rows 0,1 = tp.x,r1.x
            lo[1] = (int)permu(ur3, ur2, 0x05040100u);   // rows 2,3
            lo[2] = (int)(ur4 & 0xFFFFu);                // rows 4,5 = r4.x,0
            lo[3] = 0;                                   // rows 6,7
            hi[0] = (int)permu(ur1, utp, 0x07060302u);   // rows 8,9 = tp.y,r1.y
            hi[1] = (int)permu(ur3, ur2, 0x07060302u);   // rows 10,11
            hi[2] = (int)(ur4 >> 16);                    // rows 12,13 = r4.y,0
            hi[3] = 0;                                   // rows 14,15
            *(i32x4*)(Swp)      = lo;
            *(i32x4*)(Swp + 16) = hi;
        }

        // ---- A fragments via HW transpose read (tr elems at addr + j*32 B)
        i32x2 ta0 = tr16(tA0), ta1 = tr16(tA1);
        i32x2 tb0 = tr16(tB0), tb1 = tr16(tB1);
        LGKM0_FENCE();
        i32x4 ia0; ia0[0]=ta0[0]; ia0[1]=ta0[1]; ia0[2]=ta1[0]; ia0[3]=ta1[1];
        i32x4 ia1; ia1[0]=tb0[0]; ia1[1]=tb0[1]; ia1[2]=tb1[0]; ia1[3]=tb1[1];
        half8 af0 = __builtin_bit_cast(half8, ia0);
        half8 af1 = __builtin_bit_cast(half8, ia1);

        // ---- layer 2 GEMM: 4 N-tiles x 2 K-iters
        f32x4 acc[4];
        const f32x4 zz = {0.f, 0.f, 0.f, 0.f};
        acc[0] = MFMA(af1, B10, MFMA(af0, B00, zz));
        acc[1] = MFMA(af1, B11, MFMA(af0, B01, zz));
        acc[2] = MFMA(af1, B12, MFMA(af0, B02, zz));
        acc[3] = MFMA(af1, B13, MFMA(af0, B03, zz));

        // ---- D transpose via LDS, packed f16, path-interleaved per unit
        {
            const int p = quad >> 1;
            if (!(quad & 1)) {
                #pragma unroll
                for (int t = 0; t < 4; ++t) {
                    int2 v;
                    v.x = pk16(acc[t].x, acc[t].y);
                    v.y = pk16(acc[t].z, acc[t].w);
                    *(int2*)(wb + OFF_DV + ((t*16 + mrow) << 4) + (p << 3)) = v;
                }
            } else {
                #pragma unroll
                for (int t = 0; t < 4; ++t)
                    *(_Float16*)(wb + OFF_DA + ((t*16 + mrow) << 2) + (p << 1)) =
                        (_Float16)acc[t].x;
            }
        }

        // ---- per-lane (unit k): one b128 + one b32 read, re-pair via v_perm;
        // marshal layer-2 jets into S (2 x b128)
        const f32x4 dvv = *(const f32x4*)(wb + OFF_DV + lane*16);
        const h2 awyp   = *(const h2*)(wb + OFF_DA + lane*4);
        {
            const unsigned q0 = __builtin_bit_cast(unsigned, dvv.x); // p0 (a0,aW)
            const unsigned q1 = __builtin_bit_cast(unsigned, dvv.y); // p0 (aY,aWW)
            const unsigned q2 = __builtin_bit_cast(unsigned, dvv.z); // p1 (a0,aW)
            const unsigned q3 = __builtin_bit_cast(unsigned, dvv.w); // p1 (aY,aWW)
            const h2 a0p  = permh(q2, q0, 0x05040100);
            const h2 aWp  = permh(q2, q0, 0x07060302);
            const h2 aYp  = permh(q3, q1, 0x05040100);
            const h2 aWWp = permh(q3, q1, 0x07060302);

            const float t20 = tanh_fast(fmaf((float)a0p.x, C_2L2E, b2_s));
            const float t21 = tanh_fast(fmaf((float)a0p.y, C_2L2E, b2_s));
            const h2 t2p = pk2(t20, t21);
            const h2 d2p = hone - t2p * t2p;
            const h2 qp  = (m2h * (t2p * d2p)) * aWp;   // dd2 * aW
            const h2 s1 = d2p * aWp;
            const h2 s2 = d2p * aYp;
            const h2 s3 = qp * aWp + d2p * aWWp;
            const h2 s4 = qp * aYp + d2p * awyp;
            const unsigned ut = __builtin_bit_cast(unsigned, t2p);
            const unsigned u1 = __builtin_bit_cast(unsigned, s1);
            const unsigned u2 = __builtin_bit_cast(unsigned, s2);
            const unsigned u3 = __builtin_bit_cast(unsigned, s3);
            const unsigned u4 = __builtin_bit_cast(unsigned, s4);
            i32x4 lo, hi;
            lo[0] = (int)permu(u1, ut, 0x05040100u);
            lo[1] = (int)permu(u3, u2, 0x05040100u);
            lo[2] = (int)(u4 & 0xFFFFu);
            lo[3] = 0;
            hi[0] = (int)permu(u1, ut, 0x07060302u);
            hi[1] = (int)permu(u3, u2, 0x07060302u);
            hi[2] = (int)(u4 >> 16);
            hi[3] = 0;
            *(i32x4*)(Swp)      = lo;
            *(i32x4*)(Swp + 16) = hi;
        }

        // ---- layer 3 via MFMA (w3 broadcast over n -> all cols equal)
        i32x2 tc0 = tr16(tA0), tc1 = tr16(tA1);
        i32x2 td0 = tr16(tB0), td1 = tr16(tB1);
        LGKM0_FENCE();
        i32x4 ib0; ib0[0]=tc0[0]; ib0[1]=tc0[1]; ib0[2]=tc1[0]; ib0[3]=tc1[1];
        i32x4 ib1; ib1[0]=td0[0]; ib1[1]=td0[1]; ib1[2]=td1[0]; ib1[3]=td1[1];
        half8 bf0 = __builtin_bit_cast(half8, ib0);
        half8 bf1 = __builtin_bit_cast(half8, ib1);
        f32x4 acc4 = MFMA(bf1, W31, MFMA(bf0, W30, zz));

        // ---- policy-jet broadcast via ds_swizzle (static crossbar, 32-lane
        // groups): rows 8p..8p+3 in lane 32p regs x..w -> 0x0000 (group lane 0)
        // row 8p+4 in lane 32p+16 reg x -> 0x0200 (group lane 16)
        const float pi  = swz<0x0000>(acc4.x) + b3v;
        const float pW  = swz<0x0000>(acc4.y);
        const float pY  = swz<0x0000>(acc4.z);
        const float pWW = swz<0x0000>(acc4.w);
        const float pWY = swz<0x0200>(acc4.x);

        // ---- dynamics + jet update (refactored: shared GdtSn factor)
        const float Sn    = ksn * z1;
        const float say   = ksa * Yv;
        const float G     = fmaf(-ks2, pi, say);
        const float GdtSn = fmaf(G, C_DT, Sn);

        const float w2v  = W * W;
        const float piL  = pW * W;
        const float piLL = fmaf(pWW, w2v, piL);
        const float piY  = pY;
        const float piLY = pWY * W;

        const float pi2  = pi * pi;
        const float Lnew = fmaf(pi, fmaf(say, C_DT, Sn),
                                fmaf(-kv, pi2, L + kRdt));

        const float F_L  = fmaf(piL, GdtSn, 1.0f);
        const float F_Y  = fmaf(piY, GdtSn, kFy * pi);
        const float piL2 = piL * piL;
        const float F_LL = fmaf(piLL, GdtSn, -(ksd * piL2));
        const float F_LY = fmaf(piLY, GdtSn, piL * fmaf(-ksd, piY, kFy));

        const float gW2  = gW * gW;
        const float hWWn = fmaf(F_LL, gW2, F_L * hWW);
        const float hWYn = fmaf(F_LL, gW * gY,
                                fmaf(F_LY, gW * cYt, F_L * hWY));
        const float gWn  = F_L * gW;
        const float gYn  = fmaf(F_Y, cYt, F_L * gY);

        Yv  = fmaf(ky2, z2, fmaf(ky1, z1, cYfac * Yv));
        cYt *= cYfac;

        const float We   = __expf(Lnew);
        const bool  clip = (We < C_LBW);
        L   = clip ? C_LOGLBW : Lnew;
        W   = clip ? C_LBW    : We;
        gW  = clip ? 0.0f : gWn;
        gY  = clip ? 0.0f : gYn;
        hWW = clip ? 0.0f : hWWn;
        hWY = clip ? 0.0f : hWYn;
        tmt -= C_DT;
    }

    // terminal utility U = -0.25*exp(-4L); direct per-branch store (no atomics)
    const float E   = __expf(-4.0f * L);
    const float d1  = E * gW;
    const float d2v = fmaf(-4.0f * E, gW * gW, E * hWW);
    const float d3v = fmaf(-4.0f * E, gW * gY, E * hWY);

    if ((lane & 31) == 0) {   // lane 0 = path 2w', lane 32 = path 2w'+1
        const int branch = simb * BTOT + pg;      // 0..8191, branch&31 == i
        sd[         branch] = 0.5f * d1;
        sd[  NSIM + branch] = 0.5f * d2v;
        sd[2*NSIM + branch] = 0.5f * d3v;
    }
}

// 512 threads: 16 chunk-accumulators per eval point, LDS tree reduce.
__global__ __launch_bounds__(512) void proj_kernel(
    const float* __restrict__ sd,
    const float* __restrict__ Wp,
    const float* __restrict__ Yp,
    float* __restrict__ out)
{
    __shared__ float red[3 * 512];
    const int tid = threadIdx.x;
    const int i = tid & 31;
    const int c = tid >> 5;           // 0..15
    float lam = 0.f, dW = 0.f, dY = 0.f;
    #pragma unroll 4
    for (int jj = 0; jj < 16; ++jj) {            // 256 chunks of 32 floats total
        const int idx = i + ((jj*16 + c) << 5);  // coalesced 128B per 32 lanes
        lam += sd[idx];
        dW  += sd[NSIM + idx];
        dY  += sd[2*NSIM + idx];
    }
    red[tid] = lam; red[512 + tid] = dW; red[1024 + tid] = dY;
    __syncthreads();
    if (tid < NPTS) {
        float l = 0.f, w = 0.f, y = 0.f;
        #pragma unroll
        for (int c2 = 0; c2 < 16; ++c2) {
            l += red[c2*32 + i];
            w += red[512 + c2*32 + i];
            y += red[1024 + c2*32 + i];
        }
        l *= (1.0f / 2097152.0f);     // /128^3
        w *= (1.0f / 268435456.0f);   // /128^4
        y *= (1.0f / 268435456.0f);
        const float Wv = Wp[i], Yv = Yp[i];
        const float mmr   = C_SIGMA * (C_ALPHA * Yv);
        const float sig2  = C_SIGMA * C_SIGMA;
        const float coeff = -1.0f / (Wv * w + 1e-8f);
        const float myo   = coeff * (l * (mmr / sig2));
        const float hedge = coeff * (C_SIGMA * C_RHO * C_SIGY * y / sig2);
        float v = myo + hedge;
        v = fminf(fmaxf(v, -2.0f), 2.0f);
        out[i] = v;
    }
}

extern "C" void kernel_launch(void* const* d_in, const int* in_sizes, int n_in,
                              void* d_out, int out_size, void* d_ws, size_t ws_size,
                              hipStream_t stream) {
    const float* Wp    = (const float*)d_in[0];
    // d_in[1] = TmT (unused: reference simulates from T_H constant)
    const float* Yp    = (const float*)d_in[2];
    const float* noise = (const float*)d_in[3];
    const float* w1    = (const float*)d_in[4];
    const float* b1    = (const float*)d_in[5];
    const float* w2    = (const float*)d_in[6];
    const float* b2    = (const float*)d_in[7];
    const float* w3    = (const float*)d_in[8];
    const float* b3    = (const float*)d_in[9];
    float* out = (float*)d_out;
    float* sd  = (float*)d_ws;   // 3*8192 floats = 96 KB staging

    hipLaunchKernelGGL(sim_kernel, dim3(NBLK), dim3(256), 0, stream,
                       noise, w1, b1, w2, b2, w3, b3, Wp, Yp, sd);
    hipLaunchKernelGGL(proj_kernel, dim3(1), dim3(512), 0, stream, sd, Wp, Yp, out);
}